// Round 1
// baseline (1743.007 us; speedup 1.0000x reference)
//
#include <hip/hip_runtime.h>

#define TPB 256

// ---------------- degree / norm ----------------

__global__ void k_init_deg(float* __restrict__ deg, int n) {
    int i = blockIdx.x * TPB + threadIdx.x;
    if (i < n) deg[i] = 1.0f;   // self-loop
}

__global__ void k_count_deg(const int* __restrict__ dst, float* __restrict__ deg, int E) {
    int e = blockIdx.x * TPB + threadIdx.x;
    if (e < E) atomicAdd(&deg[dst[e]], 1.0f);
}

__global__ void k_rsqrt(float* __restrict__ deg, int n) {
    int i = blockIdx.x * TPB + threadIdx.x;
    if (i < n) deg[i] = rsqrtf(deg[i]);
}

// ---------------- dense transforms ----------------

// out[n,64] = x[n,64] @ W[64,64]; 4 rows per block, 256 threads
__global__ void k_xw64(const float* __restrict__ x, const float* __restrict__ W,
                       float* __restrict__ out, int n) {
    __shared__ float Ws[64 * 64];
    __shared__ float xs[4][64];
    int tid = threadIdx.x;
    for (int i = tid; i < 64 * 64; i += TPB) Ws[i] = W[i];
    int r = tid >> 6, c = tid & 63;
    int row = blockIdx.x * 4 + r;
    if (row < n) xs[r][c] = x[(size_t)row * 64 + c];
    __syncthreads();
    if (row < n) {
        float acc = 0.f;
#pragma unroll
        for (int k = 0; k < 64; ++k) acc += xs[r][k] * Ws[k * 64 + c];
        out[(size_t)row * 64 + c] = acc;
    }
}

// out[n,19] = x[n,64] @ W[64,19]; 8 rows per block, 32 threads/row (19 active)
__global__ void k_xw19(const float* __restrict__ x, const float* __restrict__ W,
                       float* __restrict__ out, int n) {
    __shared__ float Ws[64][20];
    __shared__ float xs[8][64];
    int tid = threadIdx.x;
    for (int i = tid; i < 64 * 19; i += TPB) Ws[i / 19][i % 19] = W[i];
    for (int i = tid; i < 8 * 64; i += TPB) {
        int rr = i >> 6, cc = i & 63;
        int row = blockIdx.x * 8 + rr;
        if (row < n) xs[rr][cc] = x[(size_t)row * 64 + cc];
    }
    __syncthreads();
    int r = tid >> 5, c = tid & 31;
    int row = blockIdx.x * 8 + r;
    if (row < n && c < 19) {
        float acc = 0.f;
#pragma unroll
        for (int k = 0; k < 64; ++k) acc += xs[r][k] * Ws[k][c];
        out[(size_t)row * 19 + c] = acc;
    }
}

// ---------------- scatter aggregation ----------------

// h[i,:] = dinv[i]^2 * hw[i,:]   (self-loop contribution, also zero-inits)
__global__ void k_selfloop64(const float* __restrict__ dinv, const float* __restrict__ hw,
                             float* __restrict__ h, int n) {
    size_t i = (size_t)blockIdx.x * TPB + threadIdx.x;
    if (i < (size_t)n * 64) {
        int node = (int)(i >> 6);
        float dv = dinv[node];
        h[i] = dv * dv * hw[i];
    }
}

// 16 threads per edge, float4 gather, 4 atomics each
__global__ void k_agg64(const int* __restrict__ src, const int* __restrict__ dst,
                        const float* __restrict__ dinv, const float* __restrict__ hw,
                        float* __restrict__ h, int E) {
    unsigned gid = blockIdx.x * TPB + threadIdx.x;
    unsigned e = gid >> 4;
    if (e >= (unsigned)E) return;
    unsigned q = gid & 15;
    int s = src[e], d = dst[e];
    float nrm = dinv[s] * dinv[d];
    float4 v = reinterpret_cast<const float4*>(hw)[(size_t)s * 16 + q];
    float* hp = h + (size_t)d * 64 + q * 4;
    atomicAdd(hp + 0, nrm * v.x);
    atomicAdd(hp + 1, nrm * v.y);
    atomicAdd(hp + 2, nrm * v.z);
    atomicAdd(hp + 3, nrm * v.w);
}

__global__ void k_relu_bias(float* __restrict__ h, const float* __restrict__ b, int n) {
    size_t i = (size_t)blockIdx.x * TPB + threadIdx.x;
    if (i < (size_t)n * 64) {
        int c = (int)(i & 63);
        float v = h[i] + b[c];
        h[i] = v > 0.f ? v : 0.f;
    }
}

// out[i,:] = dinv[i]^2 * hw2[i,:] + b2[:]   (self-loop + bias, zero-inits d_out)
__global__ void k_selfloop19(const float* __restrict__ dinv, const float* __restrict__ hw2,
                             const float* __restrict__ b2, float* __restrict__ out, int n) {
    unsigned i = blockIdx.x * TPB + threadIdx.x;
    if (i < (unsigned)n * 19u) {
        unsigned node = i / 19u;
        unsigned c = i - node * 19u;
        float dv = dinv[node];
        out[i] = dv * dv * hw2[i] + b2[c];
    }
}

// one thread per (edge, out-feature)
__global__ void k_agg19(const int* __restrict__ src, const int* __restrict__ dst,
                        const float* __restrict__ dinv, const float* __restrict__ hw2,
                        float* __restrict__ out, int E) {
    unsigned gid = blockIdx.x * TPB + threadIdx.x;
    unsigned e = gid / 19u;
    if (e >= (unsigned)E) return;
    unsigned c = gid - e * 19u;
    int s = src[e], d = dst[e];
    float nrm = dinv[s] * dinv[d];
    atomicAdd(&out[(size_t)d * 19 + c], nrm * hw2[(size_t)s * 19 + c]);
}

// ---------------- launch ----------------

extern "C" void kernel_launch(void* const* d_in, const int* in_sizes, int n_in,
                              void* d_out, int out_size, void* d_ws, size_t ws_size,
                              hipStream_t stream) {
    const float* x  = (const float*)d_in[0];
    const int*   ei = (const int*)d_in[1];
    const float* W1 = (const float*)d_in[2];
    const float* b1 = (const float*)d_in[3];
    const float* W2 = (const float*)d_in[4];
    const float* b2 = (const float*)d_in[5];
    float* out = (float*)d_out;

    int N = in_sizes[0] / 64;
    int E = in_sizes[1] / 2;
    const int* src = ei;
    const int* dst = ei + E;

    float* ws = (float*)d_ws;
    size_t oN = ((size_t)N + 63) & ~(size_t)63;
    float* deg = ws;                 // N (becomes dinv)
    float* hw1 = ws + oN;            // N*64
    float* h   = hw1 + (size_t)N * 64;  // N*64
    float* hw2 = h + (size_t)N * 64;    // N*19

    int gN   = (N + TPB - 1) / TPB;
    int gE   = (E + TPB - 1) / TPB;
    int gN64 = (int)(((size_t)N * 64 + TPB - 1) / TPB);
    int gN19 = (int)(((size_t)N * 19 + TPB - 1) / TPB);
    int gE16 = (int)(((size_t)E * 16 + TPB - 1) / TPB);
    int gE19 = (int)(((size_t)E * 19 + TPB - 1) / TPB);

    k_init_deg<<<gN, TPB, 0, stream>>>(deg, N);
    k_count_deg<<<gE, TPB, 0, stream>>>(dst, deg, E);
    k_rsqrt<<<gN, TPB, 0, stream>>>(deg, N);

    k_xw64<<<(N + 3) / 4, TPB, 0, stream>>>(x, W1, hw1, N);
    k_selfloop64<<<gN64, TPB, 0, stream>>>(deg, hw1, h, N);
    k_agg64<<<gE16, TPB, 0, stream>>>(src, dst, deg, hw1, h, E);
    k_relu_bias<<<gN64, TPB, 0, stream>>>(h, b1, N);

    k_xw19<<<(N + 7) / 8, TPB, 0, stream>>>(h, W2, hw2, N);
    k_selfloop19<<<gN19, TPB, 0, stream>>>(deg, hw2, b2, out, N);
    k_agg19<<<gE19, TPB, 0, stream>>>(src, dst, deg, hw2, out, E);
}

// Round 2
// 406.771 us; speedup vs baseline: 4.2850x; 4.2850x over previous
//
#include <hip/hip_runtime.h>

#define TPB 256

// ---------------- degree / CSR build ----------------

__global__ void k_zero2(int* __restrict__ a, int* __restrict__ b, int n) {
    int i = blockIdx.x * TPB + threadIdx.x;
    if (i < n) { a[i] = 0; b[i] = 0; }
}

__global__ void k_hist(const int* __restrict__ dst, int* __restrict__ deg, int E) {
    int e = blockIdx.x * TPB + threadIdx.x;
    if (e < E) atomicAdd(&deg[dst[e]], 1);
}

__global__ void k_dinv(const int* __restrict__ deg, float* __restrict__ dinv, int n) {
    int i = blockIdx.x * TPB + threadIdx.x;
    if (i < n) dinv[i] = rsqrtf((float)deg[i] + 1.0f);  // +1 self-loop
}

// block-level Hillis-Steele inclusive scan -> exclusive per-element + block sums
__global__ void k_scan1(const int* __restrict__ deg, int* __restrict__ excl,
                        int* __restrict__ bsum, int n) {
    __shared__ int s[TPB];
    int i = blockIdx.x * TPB + threadIdx.x;
    int v = (i < n) ? deg[i] : 0;
    s[threadIdx.x] = v;
    __syncthreads();
    for (int off = 1; off < TPB; off <<= 1) {
        int t = (threadIdx.x >= off) ? s[threadIdx.x - off] : 0;
        __syncthreads();
        s[threadIdx.x] += t;
        __syncthreads();
    }
    if (i < n) excl[i] = s[threadIdx.x] - v;
    if (threadIdx.x == TPB - 1) bsum[blockIdx.x] = s[TPB - 1];
}

// single-block exclusive scan of block sums (nb <= 512)
__global__ void k_scan2(int* __restrict__ bsum, int nb) {
    __shared__ int s[512];
    int v = (threadIdx.x < nb) ? bsum[threadIdx.x] : 0;
    s[threadIdx.x] = v;
    __syncthreads();
    for (int off = 1; off < 512; off <<= 1) {
        int t = (threadIdx.x >= off) ? s[threadIdx.x - off] : 0;
        __syncthreads();
        s[threadIdx.x] += t;
        __syncthreads();
    }
    if (threadIdx.x < nb) bsum[threadIdx.x] = s[threadIdx.x] - v;
}

__global__ void k_scan3(int* __restrict__ excl, const int* __restrict__ bsum, int n) {
    int i = blockIdx.x * TPB + threadIdx.x;
    if (i < n) excl[i] += bsum[blockIdx.x];
}

__global__ void k_fill(const int* __restrict__ src, const int* __restrict__ dst,
                       const int* __restrict__ csr_off, int* __restrict__ cnt,
                       int* __restrict__ csr_src, int E) {
    int e = blockIdx.x * TPB + threadIdx.x;
    if (e < E) {
        int d = dst[e];
        int slot = csr_off[d] + atomicAdd(&cnt[d], 1);
        csr_src[slot] = src[e];
    }
}

// ---------------- dense transforms (pre-scaled by dinv[row]) ----------------

// g[row,:] = dinv[row] * (x[row,:] @ W[64,64]); 4 rows/block
__global__ void k_xw64s(const float* __restrict__ x, const float* __restrict__ W,
                        const float* __restrict__ dinv, float* __restrict__ g, int n) {
    __shared__ float Ws[64 * 64];
    __shared__ float xs[4][64];
    int tid = threadIdx.x;
    for (int i = tid; i < 64 * 64; i += TPB) Ws[i] = W[i];
    int r = tid >> 6, c = tid & 63;
    int row = blockIdx.x * 4 + r;
    if (row < n) xs[r][c] = x[(size_t)row * 64 + c];
    __syncthreads();
    if (row < n) {
        float acc = 0.f;
#pragma unroll
        for (int k = 0; k < 64; ++k) acc += xs[r][k] * Ws[k * 64 + c];
        g[(size_t)row * 64 + c] = dinv[row] * acc;
    }
}

// g2[row,:19] = dinv[row] * (h[row,:] @ W2[64,19]); 8 rows/block
__global__ void k_xw19s(const float* __restrict__ h, const float* __restrict__ W,
                        const float* __restrict__ dinv, float* __restrict__ g2, int n) {
    __shared__ float Ws[64][20];
    __shared__ float xs[8][64];
    int tid = threadIdx.x;
    for (int i = tid; i < 64 * 19; i += TPB) Ws[i / 19][i % 19] = W[i];
    for (int i = tid; i < 8 * 64; i += TPB) {
        int rr = i >> 6, cc = i & 63;
        int row = blockIdx.x * 8 + rr;
        if (row < n) xs[rr][cc] = h[(size_t)row * 64 + cc];
    }
    __syncthreads();
    int r = tid >> 5, c = tid & 31;
    int row = blockIdx.x * 8 + r;
    if (row < n && c < 19) {
        float acc = 0.f;
#pragma unroll
        for (int k = 0; k < 64; ++k) acc += xs[r][k] * Ws[k][c];
        g2[(size_t)row * 19 + c] = dinv[row] * acc;
    }
}

// ---------------- gather aggregation (no atomics) ----------------

// h[d,c] = relu(dinv[d]*(g[d,c] + sum_{s in in(d)} g[s,c]) + b1[c]); 1 wave/node
__global__ void k_gather64(const int* __restrict__ csr_off, const int* __restrict__ deg,
                           const int* __restrict__ csr_src, const float* __restrict__ dinv,
                           const float* __restrict__ g, const float* __restrict__ b1,
                           float* __restrict__ h, int n) {
    int node = blockIdx.x * 4 + (threadIdx.x >> 6);
    if (node >= n) return;
    int lane = threadIdx.x & 63;
    int beg = csr_off[node], cnt = deg[node];
    float acc = g[(size_t)node * 64 + lane];   // self-loop
    float acc2 = 0.f;
    int k = 0;
    for (; k + 1 < cnt; k += 2) {
        int s0 = csr_src[beg + k];
        int s1 = csr_src[beg + k + 1];
        acc  += g[(size_t)s0 * 64 + lane];
        acc2 += g[(size_t)s1 * 64 + lane];
    }
    if (k < cnt) acc += g[(size_t)csr_src[beg + k] * 64 + lane];
    float v = dinv[node] * (acc + acc2) + b1[lane];
    h[(size_t)node * 64 + lane] = fmaxf(v, 0.f);
}

// out[d,c] = dinv[d]*(g2[d,c] + sum g2[s,c]) + b2[c]; 32 lanes/node (19 active)
__global__ void k_gather19(const int* __restrict__ csr_off, const int* __restrict__ deg,
                           const int* __restrict__ csr_src, const float* __restrict__ dinv,
                           const float* __restrict__ g2, const float* __restrict__ b2,
                           float* __restrict__ out, int n) {
    int node = blockIdx.x * 8 + (threadIdx.x >> 5);
    if (node >= n) return;
    int c = threadIdx.x & 31;
    if (c >= 19) return;
    int beg = csr_off[node], cnt = deg[node];
    float acc = g2[(size_t)node * 19 + c];     // self-loop
    float acc2 = 0.f;
    int k = 0;
    for (; k + 1 < cnt; k += 2) {
        int s0 = csr_src[beg + k];
        int s1 = csr_src[beg + k + 1];
        acc  += g2[(size_t)s0 * 19 + c];
        acc2 += g2[(size_t)s1 * 19 + c];
    }
    if (k < cnt) acc += g2[(size_t)csr_src[beg + k] * 19 + c];
    out[(size_t)node * 19 + c] = dinv[node] * (acc + acc2) + b2[c];
}

// ---------------- launch ----------------

extern "C" void kernel_launch(void* const* d_in, const int* in_sizes, int n_in,
                              void* d_out, int out_size, void* d_ws, size_t ws_size,
                              hipStream_t stream) {
    const float* x  = (const float*)d_in[0];
    const int*   ei = (const int*)d_in[1];
    const float* W1 = (const float*)d_in[2];
    const float* b1 = (const float*)d_in[3];
    const float* W2 = (const float*)d_in[4];
    const float* b2 = (const float*)d_in[5];
    float* out = (float*)d_out;

    int N = in_sizes[0] / 64;
    int E = in_sizes[1] / 2;
    const int* src = ei;
    const int* dst = ei + E;

    char* w = (char*)d_ws;
    int* degi    = (int*)w;  w += (size_t)N * 4;
    int* csr_off = (int*)w;  w += (size_t)N * 4;
    int* cnt     = (int*)w;  w += (size_t)N * 4;
    int* bsum    = (int*)w;  w += 512 * 4;
    int* csr_src = (int*)w;  w += (size_t)E * 4;
    float* dinv  = (float*)w; w += (size_t)N * 4;
    float* g1    = (float*)w; w += (size_t)N * 64 * 4;
    float* h     = (float*)w; w += (size_t)N * 64 * 4;
    float* g2    = g1;  // g1 dead after k_gather64; reuse for layer-2 transform

    int gN = (N + TPB - 1) / TPB;   // also = scan1 block count (nb <= 512 req.)
    int gE = (E + TPB - 1) / TPB;

    k_zero2<<<gN, TPB, 0, stream>>>(degi, cnt, N);
    k_hist <<<gE, TPB, 0, stream>>>(dst, degi, E);
    k_dinv <<<gN, TPB, 0, stream>>>(degi, dinv, N);
    k_scan1<<<gN, TPB, 0, stream>>>(degi, csr_off, bsum, N);
    k_scan2<<<1, 512, 0, stream>>>(bsum, gN);
    k_scan3<<<gN, TPB, 0, stream>>>(csr_off, bsum, N);
    k_fill <<<gE, TPB, 0, stream>>>(src, dst, csr_off, cnt, csr_src, E);

    k_xw64s   <<<(N + 3) / 4, TPB, 0, stream>>>(x, W1, dinv, g1, N);
    k_gather64<<<(N + 3) / 4, TPB, 0, stream>>>(csr_off, degi, csr_src, dinv, g1, b1, h, N);

    k_xw19s   <<<(N + 7) / 8, TPB, 0, stream>>>(h, W2, dinv, g2, N);
    k_gather19<<<(N + 7) / 8, TPB, 0, stream>>>(csr_off, degi, csr_src, dinv, g2, b2, out, N);
}

// Round 3
// 357.096 us; speedup vs baseline: 4.8811x; 1.1391x over previous
//
#include <hip/hip_runtime.h>

#define TPB 256

// ---------------- degree / CSR build ----------------

__global__ void k_zero1(int* __restrict__ a, int n) {
    int i = blockIdx.x * TPB + threadIdx.x;
    if (i < n) a[i] = 0;
}

// histogram + per-edge rank within its dst bucket (one atomic pass total)
__global__ void k_histrank(const int* __restrict__ dst, int* __restrict__ deg,
                           int* __restrict__ rank, int E) {
    int e = blockIdx.x * TPB + threadIdx.x;
    if (e < E) rank[e] = atomicAdd(&deg[dst[e]], 1);
}

__global__ void k_dinv(const int* __restrict__ deg, float* __restrict__ dinv, int n) {
    int i = blockIdx.x * TPB + threadIdx.x;
    if (i < n) dinv[i] = rsqrtf((float)deg[i] + 1.0f);  // +1 self-loop
}

// block-level Hillis-Steele inclusive scan -> exclusive per-element + block sums
__global__ void k_scan1(const int* __restrict__ deg, int* __restrict__ excl,
                        int* __restrict__ bsum, int n) {
    __shared__ int s[TPB];
    int i = blockIdx.x * TPB + threadIdx.x;
    int v = (i < n) ? deg[i] : 0;
    s[threadIdx.x] = v;
    __syncthreads();
    for (int off = 1; off < TPB; off <<= 1) {
        int t = (threadIdx.x >= off) ? s[threadIdx.x - off] : 0;
        __syncthreads();
        s[threadIdx.x] += t;
        __syncthreads();
    }
    if (i < n) excl[i] = s[threadIdx.x] - v;
    if (threadIdx.x == TPB - 1) bsum[blockIdx.x] = s[TPB - 1];
}

// single-block exclusive scan of block sums (nb <= 512)
__global__ void k_scan2(int* __restrict__ bsum, int nb) {
    __shared__ int s[512];
    int v = (threadIdx.x < nb) ? bsum[threadIdx.x] : 0;
    s[threadIdx.x] = v;
    __syncthreads();
    for (int off = 1; off < 512; off <<= 1) {
        int t = (threadIdx.x >= off) ? s[threadIdx.x - off] : 0;
        __syncthreads();
        s[threadIdx.x] += t;
        __syncthreads();
    }
    if (threadIdx.x < nb) bsum[threadIdx.x] = s[threadIdx.x] - v;
}

__global__ void k_scan3(int* __restrict__ excl, const int* __restrict__ bsum, int n) {
    int i = blockIdx.x * TPB + threadIdx.x;
    if (i < n) excl[i] += bsum[blockIdx.x];
}

// atomic-free CSR fill: slot = csr_off[dst] + precomputed rank; nt scatter store
__global__ void k_fill2(const int* __restrict__ src, const int* __restrict__ dst,
                        const int* __restrict__ rank, const int* __restrict__ csr_off,
                        int* __restrict__ csr_src, int E) {
    int e = blockIdx.x * TPB + threadIdx.x;
    if (e < E) {
        int slot = csr_off[dst[e]] + rank[e];
        __builtin_nontemporal_store(src[e], &csr_src[slot]);
    }
}

// ---------------- dense transforms (pre-scaled by dinv[row]) ----------------

// g[row,:] = dinv[row] * (x[row,:] @ W[64,64]); 4 rows/block
__global__ void k_xw64s(const float* __restrict__ x, const float* __restrict__ W,
                        const float* __restrict__ dinv, float* __restrict__ g, int n) {
    __shared__ float Ws[64 * 64];
    __shared__ float xs[4][64];
    int tid = threadIdx.x;
    for (int i = tid; i < 64 * 64; i += TPB) Ws[i] = W[i];
    int r = tid >> 6, c = tid & 63;
    int row = blockIdx.x * 4 + r;
    if (row < n) xs[r][c] = x[(size_t)row * 64 + c];
    __syncthreads();
    if (row < n) {
        float acc = 0.f;
#pragma unroll
        for (int k = 0; k < 64; ++k) acc += xs[r][k] * Ws[k * 64 + c];
        g[(size_t)row * 64 + c] = dinv[row] * acc;
    }
}

// g2[row,:19] = dinv[row] * (h[row,:] @ W2[64,19]); 8 rows/block
__global__ void k_xw19s(const float* __restrict__ h, const float* __restrict__ W,
                        const float* __restrict__ dinv, float* __restrict__ g2, int n) {
    __shared__ float Ws[64][20];
    __shared__ float xs[8][64];
    int tid = threadIdx.x;
    for (int i = tid; i < 64 * 19; i += TPB) Ws[i / 19][i % 19] = W[i];
    for (int i = tid; i < 8 * 64; i += TPB) {
        int rr = i >> 6, cc = i & 63;
        int row = blockIdx.x * 8 + rr;
        if (row < n) xs[rr][cc] = h[(size_t)row * 64 + cc];
    }
    __syncthreads();
    int r = tid >> 5, c = tid & 31;
    int row = blockIdx.x * 8 + r;
    if (row < n && c < 19) {
        float acc = 0.f;
#pragma unroll
        for (int k = 0; k < 64; ++k) acc += xs[r][k] * Ws[k][c];
        g2[(size_t)row * 19 + c] = dinv[row] * acc;
    }
}

// ---------------- gather aggregation (no atomics) ----------------

// h[d,c] = relu(dinv[d]*(g[d,c] + sum_{s in in(d)} g[s,c]) + b1[c]); 1 wave/node
__global__ void k_gather64(const int* __restrict__ csr_off, const int* __restrict__ deg,
                           const int* __restrict__ csr_src, const float* __restrict__ dinv,
                           const float* __restrict__ g, const float* __restrict__ b1,
                           float* __restrict__ h, int n) {
    int node = blockIdx.x * 4 + (threadIdx.x >> 6);
    if (node >= n) return;
    int lane = threadIdx.x & 63;
    int beg = csr_off[node], cnt = deg[node];
    float acc = g[(size_t)node * 64 + lane];   // self-loop
    float acc2 = 0.f;
    int k = 0;
    for (; k + 1 < cnt; k += 2) {
        int s0 = csr_src[beg + k];
        int s1 = csr_src[beg + k + 1];
        acc  += g[(size_t)s0 * 64 + lane];
        acc2 += g[(size_t)s1 * 64 + lane];
    }
    if (k < cnt) acc += g[(size_t)csr_src[beg + k] * 64 + lane];
    float v = dinv[node] * (acc + acc2) + b1[lane];
    h[(size_t)node * 64 + lane] = fmaxf(v, 0.f);
}

// out[d,c] = dinv[d]*(g2[d,c] + sum g2[s,c]) + b2[c]; 32 lanes/node (19 active)
__global__ void k_gather19(const int* __restrict__ csr_off, const int* __restrict__ deg,
                           const int* __restrict__ csr_src, const float* __restrict__ dinv,
                           const float* __restrict__ g2, const float* __restrict__ b2,
                           float* __restrict__ out, int n) {
    int node = blockIdx.x * 8 + (threadIdx.x >> 5);
    if (node >= n) return;
    int c = threadIdx.x & 31;
    if (c >= 19) return;
    int beg = csr_off[node], cnt = deg[node];
    float acc = g2[(size_t)node * 19 + c];     // self-loop
    float acc2 = 0.f;
    int k = 0;
    for (; k + 1 < cnt; k += 2) {
        int s0 = csr_src[beg + k];
        int s1 = csr_src[beg + k + 1];
        acc  += g2[(size_t)s0 * 19 + c];
        acc2 += g2[(size_t)s1 * 19 + c];
    }
    if (k < cnt) acc += g2[(size_t)csr_src[beg + k] * 19 + c];
    out[(size_t)node * 19 + c] = dinv[node] * (acc + acc2) + b2[c];
}

// ---------------- launch ----------------

extern "C" void kernel_launch(void* const* d_in, const int* in_sizes, int n_in,
                              void* d_out, int out_size, void* d_ws, size_t ws_size,
                              hipStream_t stream) {
    const float* x  = (const float*)d_in[0];
    const int*   ei = (const int*)d_in[1];
    const float* W1 = (const float*)d_in[2];
    const float* b1 = (const float*)d_in[3];
    const float* W2 = (const float*)d_in[4];
    const float* b2 = (const float*)d_in[5];
    float* out = (float*)d_out;

    int N = in_sizes[0] / 64;
    int E = in_sizes[1] / 2;
    const int* src = ei;
    const int* dst = ei + E;

    char* w = (char*)d_ws;
    int* degi    = (int*)w;  w += (size_t)N * 4;
    int* csr_off = (int*)w;  w += (size_t)N * 4;
    int* bsum    = (int*)w;  w += 512 * 4;
    int* rank    = (int*)w;  w += (size_t)E * 4;
    int* csr_src = (int*)w;  w += (size_t)E * 4;
    float* dinv  = (float*)w; w += (size_t)N * 4;
    float* g1    = (float*)w; w += (size_t)N * 64 * 4;
    float* h     = (float*)w; w += (size_t)N * 64 * 4;
    float* g2    = g1;  // g1 dead after k_gather64; reuse for layer-2 transform

    int gN = (N + TPB - 1) / TPB;   // scan1 block count (must be <= 512)
    int gE = (E + TPB - 1) / TPB;

    k_zero1   <<<gN, TPB, 0, stream>>>(degi, N);
    k_histrank<<<gE, TPB, 0, stream>>>(dst, degi, rank, E);
    k_dinv    <<<gN, TPB, 0, stream>>>(degi, dinv, N);
    k_scan1   <<<gN, TPB, 0, stream>>>(degi, csr_off, bsum, N);
    k_scan2   <<<1, 512, 0, stream>>>(bsum, gN);
    k_scan3   <<<gN, TPB, 0, stream>>>(csr_off, bsum, N);
    k_fill2   <<<gE, TPB, 0, stream>>>(src, dst, rank, csr_off, csr_src, E);

    k_xw64s   <<<(N + 3) / 4, TPB, 0, stream>>>(x, W1, dinv, g1, N);
    k_gather64<<<(N + 3) / 4, TPB, 0, stream>>>(csr_off, degi, csr_src, dinv, g1, b1, h, N);

    k_xw19s   <<<(N + 7) / 8, TPB, 0, stream>>>(h, W2, dinv, g2, N);
    k_gather19<<<(N + 7) / 8, TPB, 0, stream>>>(csr_off, degi, csr_src, dinv, g2, b2, out, N);
}

// Round 4
// 304.350 us; speedup vs baseline: 5.7270x; 1.1733x over previous
//
#include <hip/hip_runtime.h>

#define TPB 256

// ---------------- degree / CSR build ----------------

__global__ void k_zero1(int* __restrict__ a, int n) {
    int i = blockIdx.x * TPB + threadIdx.x;
    if (i < n) a[i] = 0;
}

// histogram + per-edge rank within its dst bucket (one atomic pass total)
__global__ void k_histrank(const int* __restrict__ dst, int* __restrict__ deg,
                           unsigned short* __restrict__ rank, int E) {
    int e = blockIdx.x * TPB + threadIdx.x;
    if (e < E) rank[e] = (unsigned short)atomicAdd(&deg[dst[e]], 1);
}

// block scan -> exclusive offsets + block sums; also emits dinv = rsqrt(deg+1)
__global__ void k_scan1(const int* __restrict__ deg, int* __restrict__ excl,
                        int* __restrict__ bsum, float* __restrict__ dinv, int n) {
    __shared__ int s[TPB];
    int i = blockIdx.x * TPB + threadIdx.x;
    int v = (i < n) ? deg[i] : 0;
    if (i < n) dinv[i] = rsqrtf((float)v + 1.0f);  // +1 self-loop
    s[threadIdx.x] = v;
    __syncthreads();
    for (int off = 1; off < TPB; off <<= 1) {
        int t = (threadIdx.x >= off) ? s[threadIdx.x - off] : 0;
        __syncthreads();
        s[threadIdx.x] += t;
        __syncthreads();
    }
    if (i < n) excl[i] = s[threadIdx.x] - v;
    if (threadIdx.x == TPB - 1) bsum[blockIdx.x] = s[TPB - 1];
}

// single-block exclusive scan of block sums (nb <= 512)
__global__ void k_scan2(int* __restrict__ bsum, int nb) {
    __shared__ int s[512];
    int v = (threadIdx.x < nb) ? bsum[threadIdx.x] : 0;
    s[threadIdx.x] = v;
    __syncthreads();
    for (int off = 1; off < 512; off <<= 1) {
        int t = (threadIdx.x >= off) ? s[threadIdx.x - off] : 0;
        __syncthreads();
        s[threadIdx.x] += t;
        __syncthreads();
    }
    if (threadIdx.x < nb) bsum[threadIdx.x] = s[threadIdx.x] - v;
}

__global__ void k_scan3(int* __restrict__ excl, const int* __restrict__ bsum, int n) {
    int i = blockIdx.x * TPB + threadIdx.x;
    if (i < n) excl[i] += bsum[blockIdx.x];
}

// atomic-free CSR fill: slot = csr_off[dst] + precomputed rank; nt scatter store
__global__ void k_fill2(const int* __restrict__ src, const int* __restrict__ dst,
                        const unsigned short* __restrict__ rank,
                        const int* __restrict__ csr_off,
                        int* __restrict__ csr_src, int E) {
    int e = blockIdx.x * TPB + threadIdx.x;
    if (e < E) {
        int slot = csr_off[dst[e]] + (int)rank[e];
        __builtin_nontemporal_store(src[e], &csr_src[slot]);
    }
}

// ---------------- dense transforms (pre-scaled by dinv[row], fp16 out) ------

// g[row,:] = fp16( dinv[row] * (x[row,:] @ W[64,64]) ); 4 rows/block
__global__ void k_xw64s(const float* __restrict__ x, const float* __restrict__ W,
                        const float* __restrict__ dinv, _Float16* __restrict__ g, int n) {
    __shared__ float Ws[64 * 64];
    __shared__ float xs[4][64];
    int tid = threadIdx.x;
    for (int i = tid; i < 64 * 64; i += TPB) Ws[i] = W[i];
    int r = tid >> 6, c = tid & 63;
    int row = blockIdx.x * 4 + r;
    if (row < n) xs[r][c] = x[(size_t)row * 64 + c];
    __syncthreads();
    if (row < n) {
        float acc = 0.f;
#pragma unroll
        for (int k = 0; k < 64; ++k) acc += xs[r][k] * Ws[k * 64 + c];
        g[(size_t)row * 64 + c] = (_Float16)(dinv[row] * acc);
    }
}

// g2[row,:19] = fp16( dinv[row] * (h[row,:] @ W2[64,19]) ); 8 rows/block; h is fp16
__global__ void k_xw19s(const _Float16* __restrict__ h, const float* __restrict__ W,
                        const float* __restrict__ dinv, _Float16* __restrict__ g2, int n) {
    __shared__ float Ws[64][20];
    __shared__ float xs[8][64];
    int tid = threadIdx.x;
    for (int i = tid; i < 64 * 19; i += TPB) Ws[i / 19][i % 19] = W[i];
    for (int i = tid; i < 8 * 64; i += TPB) {
        int rr = i >> 6, cc = i & 63;
        int row = blockIdx.x * 8 + rr;
        if (row < n) xs[rr][cc] = (float)h[(size_t)row * 64 + cc];
    }
    __syncthreads();
    int r = tid >> 5, c = tid & 31;
    int row = blockIdx.x * 8 + r;
    if (row < n && c < 19) {
        float acc = 0.f;
#pragma unroll
        for (int k = 0; k < 64; ++k) acc += xs[r][k] * Ws[k][c];
        g2[(size_t)row * 19 + c] = (_Float16)(dinv[row] * acc);
    }
}

// ---------------- gather aggregation (no atomics, fp16 payload) -------------

// h[d,c] = fp16(relu(dinv[d]*(g[d,c] + sum_{s in in(d)} g[s,c]) + b1[c])); 1 wave/node
__global__ void k_gather64(const int* __restrict__ csr_off, const int* __restrict__ deg,
                           const int* __restrict__ csr_src, const float* __restrict__ dinv,
                           const _Float16* __restrict__ g, const float* __restrict__ b1,
                           _Float16* __restrict__ h, int n) {
    int node = blockIdx.x * 4 + (threadIdx.x >> 6);
    if (node >= n) return;
    int lane = threadIdx.x & 63;
    int beg = csr_off[node], cnt = deg[node];
    float a0 = (float)g[(size_t)node * 64 + lane];   // self-loop
    float a1 = 0.f, a2 = 0.f, a3 = 0.f;
    int k = 0;
    for (; k + 3 < cnt; k += 4) {
        int s0 = csr_src[beg + k];
        int s1 = csr_src[beg + k + 1];
        int s2 = csr_src[beg + k + 2];
        int s3 = csr_src[beg + k + 3];
        a0 += (float)g[(size_t)s0 * 64 + lane];
        a1 += (float)g[(size_t)s1 * 64 + lane];
        a2 += (float)g[(size_t)s2 * 64 + lane];
        a3 += (float)g[(size_t)s3 * 64 + lane];
    }
    for (; k < cnt; ++k) a1 += (float)g[(size_t)csr_src[beg + k] * 64 + lane];
    float v = dinv[node] * ((a0 + a1) + (a2 + a3)) + b1[lane];
    h[(size_t)node * 64 + lane] = (_Float16)fmaxf(v, 0.f);
}

// out[d,c] = dinv[d]*(g2[d,c] + sum g2[s,c]) + b2[c]; 32 lanes/node (19 active)
__global__ void k_gather19(const int* __restrict__ csr_off, const int* __restrict__ deg,
                           const int* __restrict__ csr_src, const float* __restrict__ dinv,
                           const _Float16* __restrict__ g2, const float* __restrict__ b2,
                           float* __restrict__ out, int n) {
    int node = blockIdx.x * 8 + (threadIdx.x >> 5);
    if (node >= n) return;
    int c = threadIdx.x & 31;
    if (c >= 19) return;
    int beg = csr_off[node], cnt = deg[node];
    float a0 = (float)g2[(size_t)node * 19 + c];     // self-loop
    float a1 = 0.f, a2 = 0.f, a3 = 0.f;
    int k = 0;
    for (; k + 3 < cnt; k += 4) {
        int s0 = csr_src[beg + k];
        int s1 = csr_src[beg + k + 1];
        int s2 = csr_src[beg + k + 2];
        int s3 = csr_src[beg + k + 3];
        a0 += (float)g2[(size_t)s0 * 19 + c];
        a1 += (float)g2[(size_t)s1 * 19 + c];
        a2 += (float)g2[(size_t)s2 * 19 + c];
        a3 += (float)g2[(size_t)s3 * 19 + c];
    }
    for (; k < cnt; ++k) a1 += (float)g2[(size_t)csr_src[beg + k] * 19 + c];
    out[(size_t)node * 19 + c] = dinv[node] * ((a0 + a1) + (a2 + a3)) + b2[c];
}

// ---------------- launch ----------------

extern "C" void kernel_launch(void* const* d_in, const int* in_sizes, int n_in,
                              void* d_out, int out_size, void* d_ws, size_t ws_size,
                              hipStream_t stream) {
    const float* x  = (const float*)d_in[0];
    const int*   ei = (const int*)d_in[1];
    const float* W1 = (const float*)d_in[2];
    const float* b1 = (const float*)d_in[3];
    const float* W2 = (const float*)d_in[4];
    const float* b2 = (const float*)d_in[5];
    float* out = (float*)d_out;

    int N = in_sizes[0] / 64;
    int E = in_sizes[1] / 2;
    const int* src = ei;
    const int* dst = ei + E;

    char* w = (char*)d_ws;
    int* degi    = (int*)w;  w += (size_t)N * 4;
    int* csr_off = (int*)w;  w += (size_t)N * 4;
    int* bsum    = (int*)w;  w += 512 * 4;
    int* csr_src = (int*)w;  w += (size_t)E * 4;
    float* dinv  = (float*)w; w += (size_t)N * 4;
    unsigned short* rank = (unsigned short*)w; w += (size_t)E * 2;
    w = (char*)(((size_t)w + 63) & ~(size_t)63);
    _Float16* g1 = (_Float16*)w; w += (size_t)N * 64 * 2;
    _Float16* h  = (_Float16*)w; w += (size_t)N * 64 * 2;
    _Float16* g2 = g1;  // g1 dead after k_gather64; reuse for layer-2 transform

    int gN = (N + TPB - 1) / TPB;   // scan1 block count (must be <= 512)
    int gE = (E + TPB - 1) / TPB;

    k_zero1   <<<gN, TPB, 0, stream>>>(degi, N);
    k_histrank<<<gE, TPB, 0, stream>>>(dst, degi, rank, E);
    k_scan1   <<<gN, TPB, 0, stream>>>(degi, csr_off, bsum, dinv, N);
    k_scan2   <<<1, 512, 0, stream>>>(bsum, gN);
    k_scan3   <<<gN, TPB, 0, stream>>>(csr_off, bsum, N);
    k_fill2   <<<gE, TPB, 0, stream>>>(src, dst, rank, csr_off, csr_src, E);

    k_xw64s   <<<(N + 3) / 4, TPB, 0, stream>>>(x, W1, dinv, g1, N);
    k_gather64<<<(N + 3) / 4, TPB, 0, stream>>>(csr_off, degi, csr_src, dinv, g1, b1, h, N);

    k_xw19s   <<<(N + 7) / 8, TPB, 0, stream>>>(h, W2, dinv, g2, N);
    k_gather19<<<(N + 7) / 8, TPB, 0, stream>>>(csr_off, degi, csr_src, dinv, g2, b2, out, N);
}